// Round 1
// baseline (198.028 us; speedup 1.0000x reference)
//
#include <hip/hip_runtime.h>
#include <cstdint>

#define HDIM 256
#define MT   128      // feature rows per block (4 waves x 32 rows)
#define BD   32       // En rows per K-loop iteration
#define SPLITS 32

typedef short bf16x8 __attribute__((ext_vector_type(8)));
typedef short bf16x4 __attribute__((ext_vector_type(4)));
typedef float f32x4  __attribute__((ext_vector_type(4)));

typedef const __attribute__((address_space(1))) short as1_short;
typedef __attribute__((address_space(3))) short as3_short;

static __device__ __forceinline__ short f2bf(float x) {
    union { float f; uint32_t u; } v; v.f = x;
    uint32_t u = v.u;
    uint32_t r = (u + 0x7fffu + ((u >> 16) & 1u)) >> 16;
    return (short)r;
}

// ---- prep (single dispatch):
//  blocks [0, nb_nrm)          : L2-normalize feature/ex_feature rows -> bf16,
//                                stored with XOR-16B-chunk swizzle
//  blocks [nb_nrm, nb_nrm+128) : transpose class reps to Rt[32][D] (col C = 1.0
//                                -> intensity falls out of the echo GEMM)
__global__ __launch_bounds__(256) void prep_kernel(const float* __restrict__ fsrc,
                                                   const float* __restrict__ esrc,
                                                   const float* __restrict__ reps,
                                                   short* __restrict__ dst,
                                                   short* __restrict__ rt,
                                                   int N, int rows_total,
                                                   int D, int C, int nb_nrm) {
    __shared__ float lds[128][29];                    // +1 pad col
    const int tid = threadIdx.x;
    if ((int)blockIdx.x < nb_nrm) {
        int wv = tid >> 6;
        int lane = tid & 63;
        int row = blockIdx.x * 4 + wv;
        if (row >= rows_total) return;
        const float* src = (row < N) ? (fsrc + (size_t)row * HDIM)
                                     : (esrc + (size_t)(row - N) * HDIM);
        const float4 v = *(const float4*)(src + lane * 4);
        float ss = v.x * v.x + v.y * v.y + v.z * v.z + v.w * v.w;
        #pragma unroll
        for (int m = 1; m < 64; m <<= 1) ss += __shfl_xor(ss, m, 64);
        float scale = 1.0f / fmaxf(sqrtf(ss), 1e-12f);
        short4 o;
        o.x = f2bf(v.x * scale); o.y = f2bf(v.y * scale);
        o.z = f2bf(v.z * scale); o.w = f2bf(v.w * scale);
        int chunk = (lane >> 1) ^ (row & 7);          // swizzled 16B-chunk index
        *(short4*)(dst + (size_t)row * HDIM + chunk * 8 + (lane & 1) * 4) = o;
    } else {
        const int bx = blockIdx.x - nb_nrm;           // 0..127
        const int d0 = bx * 128;
        const int total = 128 * C;
        const float* src = reps + (size_t)d0 * C;
        for (int i = tid; i < total; i += 256)
            lds[i / C][i % C] = src[i];               // coalesced load
        __syncthreads();
        const int c = tid >> 3;                       // 0..31
        const int dsub = (tid & 7) * 16;              // 16 d per thread
        short* dstp = rt + (size_t)c * D + d0 + dsub;
        #pragma unroll
        for (int j0 = 0; j0 < 16; j0 += 4) {
            short4 o;
            float v0, v1, v2, v3;
            if (c < C) {
                v0 = lds[dsub + j0 + 0][c]; v1 = lds[dsub + j0 + 1][c];
                v2 = lds[dsub + j0 + 2][c]; v3 = lds[dsub + j0 + 3][c];
            } else {
                float f = (c == C) ? 1.0f : 0.0f;     // ones column -> intensity
                v0 = v1 = v2 = v3 = f;
            }
            o.x = f2bf(v0); o.y = f2bf(v1); o.z = f2bf(v2); o.w = f2bf(v3);
            *(short4*)(dstp + j0) = o;                // coalesced store
        }
    }
}

// ---- fused: GEMM1 computes S^T via operand-swapped MFMA (A=En, B=Fn), so the
// activated tile sits in 16x16x16 B-operand layout and feeds GEMM2
// echo^T += Rt_frag * a^T with NO LDS round-trip.
//
// r9 (this round, T15): software-pipeline the dependent tail. Iteration it
// computes GEMM1 into sT_cur while the activation VALU + GEMM2 MFMAs of
// sT_prev sit in the same scheduling region with no dependence on it's
// ds_reads/MFMAs -> scheduler weaves prev's VALU into cur's lgkm stalls
// instead of serializing [LDS+MFMA burst]->[VALU burst]->[GEMM2 burst] per
// barrier window (burst alignment across the 16 resident waves made wall ~=
// sum of pipes: Mfma 24% + VALU 21% + LDS ~35%). Static sTa/sTb ping-pong
// (rule 20), loop unrolled by 2 so no runtime parity branch.
__global__ __launch_bounds__(256, 4) void fused_kernel(const short* __restrict__ Fn,
                                                       const short* __restrict__ En,
                                                       const short* __restrict__ Rt,
                                                       const int* __restrict__ pptr,
                                                       float* __restrict__ partial,
                                                       int N, int D, int C, int Dchunk) {
    __shared__ __align__(16) short lds_en[2][BD * HDIM];   // 2 x 16 KB double buffer

    const int tid  = threadIdx.x;
    const int lane = tid & 63;
    const int wv   = tid >> 6;
    const int q    = lane >> 4;
    const int l    = lane & 15;
    const int p    = pptr[0];

    const int Mbase = blockIdx.y * MT;
    const int dbase = blockIdx.x * Dchunk;

    const f32x4 zf = {0.0f, 0.0f, 0.0f, 0.0f};

    // Fn fragments (B-operand of GEMM1): B[k=ks*32+q*8+j][n=l] — de-swizzle in
    // the address.
    bf16x8 afrag[2][8];
    #pragma unroll
    for (int fn = 0; fn < 2; ++fn) {
        const short* rowp = Fn + (size_t)(Mbase + wv * 32 + fn * 16 + l) * HDIM;
        #pragma unroll
        for (int ks = 0; ks < 8; ++ks)
            afrag[fn][ks] = *(const bf16x8*)(rowp + (((ks * 4 + q) ^ (l & 7)) << 3));
    }

    // echo^T accumulators: [f-tile][c-tile], C/D layout col=f(l), row=c(q*4+r)
    f32x4 echo_acc[2][2];
    echo_acc[0][0] = zf; echo_acc[0][1] = zf;
    echo_acc[1][0] = zf; echo_acc[1][1] = zf;

    const int iters = Dchunk / BD;       // 16: even and >= 4 by construction

    #define STAGE(buf_, it_)                                                        \
        {                                                                           \
            const short* gbase = En + (size_t)(dbase + (it_) * BD) * HDIM + tid * 8;\
            _Pragma("unroll")                                                       \
            for (int i = 0; i < 4; ++i) {                                           \
                as3_short* lp = (as3_short*)(lds_en[buf_] + (i * 256 + wv * 64) * 8);\
                __builtin_amdgcn_global_load_lds((as1_short*)(gbase + i * 2048),    \
                                                 lp, 16, 0, 0);                     \
            }                                                                       \
        }

    // GEMM1: S^T tiles [en=d-block][fn=f-tile], 32(D) x 32(M) per wave, K=256
    #define GEMM1(BUF_, ST_)                                                        \
        {                                                                           \
            ST_[0][0] = zf; ST_[0][1] = zf; ST_[1][0] = zf; ST_[1][1] = zf;         \
            _Pragma("unroll")                                                       \
            for (int ks = 0; ks < 8; ++ks) {                                        \
                _Pragma("unroll")                                                   \
                for (int en = 0; en < 2; ++en) {                                    \
                    const int row  = en * 16 + l;                                   \
                    const int slot = (ks * 4 + q) ^ (l & 7);                        \
                    bf16x8 ef = *(const bf16x8*)(lds_en[BUF_] + row * HDIM + slot * 8); \
                    ST_[en][0] = __builtin_amdgcn_mfma_f32_16x16x32_bf16(ef, afrag[0][ks], ST_[en][0], 0, 0, 0); \
                    ST_[en][1] = __builtin_amdgcn_mfma_f32_16x16x32_bf16(ef, afrag[1][ks], ST_[en][1], 0, 0, 0); \
                }                                                                   \
            }                                                                       \
        }

    // Deferred tail for iteration IT_ (whose S^T sits in ST_): issue Rt loads
    // first (L2 latency hides under the act VALU), then activation -> packed
    // bf16, then GEMM2 echo^T += Rt_frag(A) * a^T(B).
    #define ACT2(ST_, IT_)                                                          \
        {                                                                           \
            const int d0p = dbase + (IT_) * BD;                                     \
            bf16x4 rt_f[2][2];                                                      \
            _Pragma("unroll")                                                       \
            for (int dblk = 0; dblk < 2; ++dblk) {                                  \
                const int doff = d0p + dblk * 16;                                   \
                rt_f[dblk][0] = *(const bf16x4*)(rtp + doff);                       \
                rt_f[dblk][1] = *(const bf16x4*)(rtp + (size_t)16 * D + doff);      \
            }                                                                       \
            bf16x4 pfrag[2][2];                                                     \
            _Pragma("unroll")                                                       \
            for (int en = 0; en < 2; ++en) {                                        \
                _Pragma("unroll")                                                   \
                for (int fn = 0; fn < 2; ++fn) {                                    \
                    bf16x4 pf;                                                      \
                    _Pragma("unroll")                                               \
                    for (int r = 0; r < 4; ++r) {                                   \
                        float sv = ST_[en][fn][r];                                  \
                        float a;                                                    \
                        if (p == 3)      a = sv * sv * sv;                          \
                        else if (p == 1) a = sv;                                    \
                        else if (p == 2) a = sv * fabsf(sv);                        \
                        else             a = copysignf(powf(fabsf(sv), (float)p), sv); \
                        pf[r] = f2bf(a);                                            \
                    }                                                               \
                    pfrag[fn][en] = pf;                                             \
                }                                                                   \
            }                                                                       \
            _Pragma("unroll")                                                       \
            for (int dblk = 0; dblk < 2; ++dblk) {                                  \
                _Pragma("unroll")                                                   \
                for (int fn = 0; fn < 2; ++fn) {                                    \
                    echo_acc[fn][0] = __builtin_amdgcn_mfma_f32_16x16x16bf16_1k(rt_f[dblk][0], pfrag[fn][dblk], echo_acc[fn][0], 0, 0, 0); \
                    echo_acc[fn][1] = __builtin_amdgcn_mfma_f32_16x16x16bf16_1k(rt_f[dblk][1], pfrag[fn][dblk], echo_acc[fn][1], 0, 0, 0); \
                }                                                                   \
            }                                                                       \
        }

    const short* rtp = Rt + (size_t)l * D + q * 4;    // c-tile 0 row; +16*D for tile 1

    f32x4 sTa[2][2];
    f32x4 sTb[2][2];

    // ---- prologue: iterations 0 and 1 (GEMM1 only for 0; 1 starts the pipe) --
    STAGE(0, 0)
    __syncthreads();                  // stage(0) landed
    STAGE(1, 1)
    GEMM1(0, sTa)

    __syncthreads();                  // stage(1) landed; buf0 reads done
    STAGE(0, 2)
    GEMM1(1, sTb)
    ACT2(sTa, 0)

    // ---- steady state: pairs (it even, it+1 odd), tile t lives in buf t&1 ----
    for (int it = 2; it < iters; it += 2) {
        __syncthreads();              // stage(it) landed; buf0 reads done
        if (it + 1 < iters) STAGE(1, it + 1)
        GEMM1(0, sTa)
        ACT2(sTb, it - 1)

        __syncthreads();              // stage(it+1) landed; buf1 reads done
        if (it + 2 < iters) STAGE(0, it + 2)
        GEMM1(1, sTb)
        ACT2(sTa, it)
    }
    ACT2(sTb, iters - 1)              // iters even -> last tile sits in sTb

    // Epilogue: echo^T C-layout (col f = l, rows c = ct*16 + q*4 + r) -> one
    // float4 store per (f-tile, c-tile); reduce kernel ignores c > C.
    #pragma unroll
    for (int fn = 0; fn < 2; ++fn) {
        const int grow = Mbase + wv * 32 + fn * 16 + l;
        float* rowp = partial + ((size_t)blockIdx.x * N + grow) * 32 + q * 4;
        *(f32x4*)(rowp)      = echo_acc[fn][0];
        *(f32x4*)(rowp + 16) = echo_acc[fn][1];
    }

    #undef STAGE
    #undef GEMM1
    #undef ACT2
}

// ---- reduce: sum partials over splits; col<C -> echo, col==C -> intensity ----
__global__ __launch_bounds__(256) void reduce_kernel(const float* __restrict__ partial,
                                                     float* __restrict__ echo,
                                                     float* __restrict__ inten,
                                                     int N, int splits, int C) {
    int t = blockIdx.x * 256 + threadIdx.x;    // N*32 threads
    int row = t >> 5, c = t & 31;
    if (row >= N || c > C) return;
    float s = 0.0f;
    for (int k = 0; k < splits; ++k)
        s += partial[((size_t)k * N + (size_t)row) * 32 + c];
    if (c < C) echo[(size_t)row * C + c] = s;
    else       inten[row] = s;
}

extern "C" void kernel_launch(void* const* d_in, const int* in_sizes, int n_in,
                              void* d_out, int out_size, void* d_ws, size_t ws_size,
                              hipStream_t stream) {
    const int N = in_sizes[0] / HDIM;       // 4096
    const int D = in_sizes[1] / HDIM;       // 16384
    const int C = in_sizes[2] / D;          // 28

    const float* feat = (const float*)d_in[0];
    const float* exf  = (const float*)d_in[1];
    const float* reps = (const float*)d_in[2];
    const int*   p    = (const int*)d_in[3];

    short* Fn = (short*)d_ws;                          // [N][256] bf16 (swizzled)
    short* En = Fn + (size_t)N * HDIM;                 // [D][256] bf16 (swizzled)
    short* Rt = En + (size_t)D * HDIM;                 // [32][D] bf16 (col C = 1.0)
    float* partial = (float*)(Rt + (size_t)32 * D);    // [SPLITS][N][32] f32

    float* echo  = (float*)d_out;
    float* inten = echo + (size_t)N * C;

    const int nb_nrm = (N + D) / 4;
    hipLaunchKernelGGL(prep_kernel, dim3(nb_nrm + D / 128), dim3(256), 0, stream,
                       feat, exf, reps, Fn, Rt, N, N + D, D, C, nb_nrm);

    const int Dchunk = D / SPLITS;
    hipLaunchKernelGGL(fused_kernel, dim3(SPLITS, N / MT), dim3(256), 0, stream,
                       Fn, En, Rt, p, partial, N, D, C, Dchunk);

    hipLaunchKernelGGL(reduce_kernel, dim3(N * 32 / 256), dim3(256), 0, stream,
                       partial, echo, inten, N, SPLITS, C);
}

// Round 2
// 165.217 us; speedup vs baseline: 1.1986x; 1.1986x over previous
//
#include <hip/hip_runtime.h>
#include <cstdint>

#define HDIM 256
#define MT   128      // feature rows per block (4 waves x 32 rows)
#define BD   32       // En rows per K-loop iteration
#define SPLITS 32

typedef short bf16x8 __attribute__((ext_vector_type(8)));
typedef short bf16x4 __attribute__((ext_vector_type(4)));
typedef float f32x4  __attribute__((ext_vector_type(4)));

typedef const __attribute__((address_space(1))) short as1_short;
typedef __attribute__((address_space(3))) short as3_short;

// packed RNE f32->bf16 pair: one v_cvt_pk_bf16_f32 replaces ~8-10 VALU ops of
// the manual round-to-nearest-even bit sequence. Compiler cannot derive this
// from integer bit-twiddling, so it is hand-placed (r10).
static __device__ __forceinline__ uint32_t cvt_pk_bf16(float lo, float hi) {
    uint32_t r;
    asm("v_cvt_pk_bf16_f32 %0, %1, %2" : "=v"(r) : "v"(lo), "v"(hi));
    return r;
}

// ---- prep (single dispatch):
//  blocks [0, nb_nrm)          : L2-normalize feature/ex_feature rows -> bf16,
//                                stored with XOR-16B-chunk swizzle
//  blocks [nb_nrm, nb_nrm+128) : transpose class reps to Rt[32][D] (col C = 1.0
//                                -> intensity falls out of the echo GEMM)
__global__ __launch_bounds__(256) void prep_kernel(const float* __restrict__ fsrc,
                                                   const float* __restrict__ esrc,
                                                   const float* __restrict__ reps,
                                                   short* __restrict__ dst,
                                                   short* __restrict__ rt,
                                                   int N, int rows_total,
                                                   int D, int C, int nb_nrm) {
    __shared__ float lds[128][29];                    // +1 pad col
    const int tid = threadIdx.x;
    if ((int)blockIdx.x < nb_nrm) {
        int wv = tid >> 6;
        int lane = tid & 63;
        int row = blockIdx.x * 4 + wv;
        if (row >= rows_total) return;
        const float* src = (row < N) ? (fsrc + (size_t)row * HDIM)
                                     : (esrc + (size_t)(row - N) * HDIM);
        const float4 v = *(const float4*)(src + lane * 4);
        float ss = v.x * v.x + v.y * v.y + v.z * v.z + v.w * v.w;
        #pragma unroll
        for (int m = 1; m < 64; m <<= 1) ss += __shfl_xor(ss, m, 64);
        float scale = 1.0f / fmaxf(sqrtf(ss), 1e-12f);
        union { uint32_t u[2]; short4 s; } pk;
        pk.u[0] = cvt_pk_bf16(v.x * scale, v.y * scale);
        pk.u[1] = cvt_pk_bf16(v.z * scale, v.w * scale);
        int chunk = (lane >> 1) ^ (row & 7);          // swizzled 16B-chunk index
        *(short4*)(dst + (size_t)row * HDIM + chunk * 8 + (lane & 1) * 4) = pk.s;
    } else {
        const int bx = blockIdx.x - nb_nrm;           // 0..127
        const int d0 = bx * 128;
        const int total = 128 * C;
        const float* src = reps + (size_t)d0 * C;
        for (int i = tid; i < total; i += 256)
            lds[i / C][i % C] = src[i];               // coalesced load
        __syncthreads();
        const int c = tid >> 3;                       // 0..31
        const int dsub = (tid & 7) * 16;              // 16 d per thread
        short* dstp = rt + (size_t)c * D + d0 + dsub;
        #pragma unroll
        for (int j0 = 0; j0 < 16; j0 += 4) {
            float v0, v1, v2, v3;
            if (c < C) {
                v0 = lds[dsub + j0 + 0][c]; v1 = lds[dsub + j0 + 1][c];
                v2 = lds[dsub + j0 + 2][c]; v3 = lds[dsub + j0 + 3][c];
            } else {
                float f = (c == C) ? 1.0f : 0.0f;     // ones column -> intensity
                v0 = v1 = v2 = v3 = f;
            }
            union { uint32_t u[2]; short4 s; } pk;
            pk.u[0] = cvt_pk_bf16(v0, v1);
            pk.u[1] = cvt_pk_bf16(v2, v3);
            *(short4*)(dstp + j0) = pk.s;             // coalesced store
        }
    }
}

// ---- fused: GEMM1 computes S^T via operand-swapped MFMA (A=En, B=Fn), so the
// activated tile sits in 16x16x16 B-operand layout (C/D layout == B layout for
// K=16 MFMA) and feeds GEMM2 echo^T += Rt_frag * a^T with NO LDS round-trip.
// En staged via global_load_lds double buffer. XOR de-swizzle in per-lane addrs.
//
// r9 POST-MORTEM (journal): T15 deferral (second sT live across GEMM1) pushed
// the unified VGPR+AGPR allocation past the 128/wave cap imposed by
// __launch_bounds__(256,4) -> scratch spill, FETCH 18->139 MB, wall 68->121us.
// This kernel has ZERO register slack at 4 blocks/CU; pipelining must be
// register-neutral. r10 instead SHRINKS the serial VALU tail: v_cvt_pk_bf16_f32
// (packed RNE) replaces the 4-5-op manual f2bf per element (16x per iter).
__global__ __launch_bounds__(256, 4) void fused_kernel(const short* __restrict__ Fn,
                                                       const short* __restrict__ En,
                                                       const short* __restrict__ Rt,
                                                       const int* __restrict__ pptr,
                                                       float* __restrict__ partial,
                                                       int N, int D, int C, int Dchunk) {
    __shared__ __align__(16) short lds_en[2][BD * HDIM];   // 2 x 16 KB double buffer

    const int tid  = threadIdx.x;
    const int lane = tid & 63;
    const int wv   = tid >> 6;
    const int q    = lane >> 4;
    const int l    = lane & 15;
    const int p    = pptr[0];

    const int Mbase = blockIdx.y * MT;
    const int dbase = blockIdx.x * Dchunk;

    const f32x4 zf = {0.0f, 0.0f, 0.0f, 0.0f};

    // Fn fragments (B-operand of GEMM1): B[k=ks*32+q*8+j][n=l] — de-swizzle in
    // the address.
    bf16x8 afrag[2][8];
    #pragma unroll
    for (int fn = 0; fn < 2; ++fn) {
        const short* rowp = Fn + (size_t)(Mbase + wv * 32 + fn * 16 + l) * HDIM;
        #pragma unroll
        for (int ks = 0; ks < 8; ++ks)
            afrag[fn][ks] = *(const bf16x8*)(rowp + (((ks * 4 + q) ^ (l & 7)) << 3));
    }

    // echo^T accumulators: [f-tile][c-tile], C/D layout col=f(l), row=c(q*4+r)
    f32x4 echo_acc[2][2];
    echo_acc[0][0] = zf; echo_acc[0][1] = zf;
    echo_acc[1][0] = zf; echo_acc[1][1] = zf;

    const int iters = Dchunk / BD;

    #define STAGE(buf_, it_)                                                        \
        {                                                                           \
            const short* gbase = En + (size_t)(dbase + (it_) * BD) * HDIM + tid * 8;\
            _Pragma("unroll")                                                       \
            for (int i = 0; i < 4; ++i) {                                           \
                as3_short* lp = (as3_short*)(lds_en[buf_] + (i * 256 + wv * 64) * 8);\
                __builtin_amdgcn_global_load_lds((as1_short*)(gbase + i * 2048),    \
                                                 lp, 16, 0, 0);                     \
            }                                                                       \
        }

    STAGE(0, 0)

    const short* rtp = Rt + (size_t)l * D + q * 4;    // c-tile 0 row; +16*D for tile 1

    for (int it = 0; it < iters; ++it) {
        const int buf = it & 1;
        __syncthreads();                 // stage(it) landed; all waves done with buf^1
        if (it + 1 < iters) STAGE(buf ^ 1, it + 1)

        const int d0 = dbase + it * BD;

        // GEMM1: S^T tiles [en=d-block][fn=f-tile], 32(D) x 32(M) per wave, K=256
        f32x4 sT[2][2];
        sT[0][0] = zf; sT[0][1] = zf; sT[1][0] = zf; sT[1][1] = zf;
        #pragma unroll
        for (int ks = 0; ks < 8; ++ks) {
            #pragma unroll
            for (int en = 0; en < 2; ++en) {
                const int row  = en * 16 + l;
                const int slot = (ks * 4 + q) ^ (l & 7);
                bf16x8 ef = *(const bf16x8*)(lds_en[buf] + row * HDIM + slot * 8);
                sT[en][0] = __builtin_amdgcn_mfma_f32_16x16x32_bf16(ef, afrag[0][ks], sT[en][0], 0, 0, 0);
                sT[en][1] = __builtin_amdgcn_mfma_f32_16x16x32_bf16(ef, afrag[1][ks], sT[en][1], 0, 0, 0);
            }
        }

        // activation in-register -> packed bf16x4 via v_cvt_pk_bf16_f32 (r10):
        // 8 cvt_pk + 32 mul per iter instead of ~100 VALU with manual f2bf.
        bf16x4 pfrag[2][2];              // [f-tile][d-block]
        #pragma unroll
        for (int en = 0; en < 2; ++en) {
            #pragma unroll
            for (int fn = 0; fn < 2; ++fn) {
                float a0, a1, a2, a3;
                {
                    float s0 = sT[en][fn][0], s1 = sT[en][fn][1];
                    float s2 = sT[en][fn][2], s3 = sT[en][fn][3];
                    if (p == 3) {
                        a0 = s0 * s0 * s0; a1 = s1 * s1 * s1;
                        a2 = s2 * s2 * s2; a3 = s3 * s3 * s3;
                    } else if (p == 1) {
                        a0 = s0; a1 = s1; a2 = s2; a3 = s3;
                    } else if (p == 2) {
                        a0 = s0 * fabsf(s0); a1 = s1 * fabsf(s1);
                        a2 = s2 * fabsf(s2); a3 = s3 * fabsf(s3);
                    } else {
                        a0 = copysignf(powf(fabsf(s0), (float)p), s0);
                        a1 = copysignf(powf(fabsf(s1), (float)p), s1);
                        a2 = copysignf(powf(fabsf(s2), (float)p), s2);
                        a3 = copysignf(powf(fabsf(s3), (float)p), s3);
                    }
                }
                union { uint32_t u[2]; bf16x4 v; } pk;
                pk.u[0] = cvt_pk_bf16(a0, a1);
                pk.u[1] = cvt_pk_bf16(a2, a3);
                pfrag[fn][en] = pk.v;
            }
        }

        // GEMM2: echo^T += Rt_frag(A) * a^T(B), 16x16x16, K=32 via 2 d-blocks
        #pragma unroll
        for (int dblk = 0; dblk < 2; ++dblk) {
            const int doff = d0 + dblk * 16;
            bf16x4 rt0 = *(const bf16x4*)(rtp + doff);              // c-tile 0
            bf16x4 rt1 = *(const bf16x4*)(rtp + (size_t)16 * D + doff); // c-tile 1
            #pragma unroll
            for (int fn = 0; fn < 2; ++fn) {
                echo_acc[fn][0] = __builtin_amdgcn_mfma_f32_16x16x16bf16_1k(rt0, pfrag[fn][dblk], echo_acc[fn][0], 0, 0, 0);
                echo_acc[fn][1] = __builtin_amdgcn_mfma_f32_16x16x16bf16_1k(rt1, pfrag[fn][dblk], echo_acc[fn][1], 0, 0, 0);
            }
        }
    }

    // Epilogue: echo^T C-layout (col f = l, rows c = ct*16 + q*4 + r) -> one
    // float4 store per (f-tile, c-tile); reduce kernel ignores c > C.
    #pragma unroll
    for (int fn = 0; fn < 2; ++fn) {
        const int grow = Mbase + wv * 32 + fn * 16 + l;
        float* rowp = partial + ((size_t)blockIdx.x * N + grow) * 32 + q * 4;
        *(f32x4*)(rowp)      = echo_acc[fn][0];
        *(f32x4*)(rowp + 16) = echo_acc[fn][1];
    }

    #undef STAGE
}

// ---- reduce: sum partials over splits; col<C -> echo, col==C -> intensity ----
__global__ __launch_bounds__(256) void reduce_kernel(const float* __restrict__ partial,
                                                     float* __restrict__ echo,
                                                     float* __restrict__ inten,
                                                     int N, int splits, int C) {
    int t = blockIdx.x * 256 + threadIdx.x;    // N*32 threads
    int row = t >> 5, c = t & 31;
    if (row >= N || c > C) return;
    float s = 0.0f;
    for (int k = 0; k < splits; ++k)
        s += partial[((size_t)k * N + (size_t)row) * 32 + c];
    if (c < C) echo[(size_t)row * C + c] = s;
    else       inten[row] = s;
}

extern "C" void kernel_launch(void* const* d_in, const int* in_sizes, int n_in,
                              void* d_out, int out_size, void* d_ws, size_t ws_size,
                              hipStream_t stream) {
    const int N = in_sizes[0] / HDIM;       // 4096
    const int D = in_sizes[1] / HDIM;       // 16384
    const int C = in_sizes[2] / D;          // 28

    const float* feat = (const float*)d_in[0];
    const float* exf  = (const float*)d_in[1];
    const float* reps = (const float*)d_in[2];
    const int*   p    = (const int*)d_in[3];

    short* Fn = (short*)d_ws;                          // [N][256] bf16 (swizzled)
    short* En = Fn + (size_t)N * HDIM;                 // [D][256] bf16 (swizzled)
    short* Rt = En + (size_t)D * HDIM;                 // [32][D] bf16 (col C = 1.0)
    float* partial = (float*)(Rt + (size_t)32 * D);    // [SPLITS][N][32] f32

    float* echo  = (float*)d_out;
    float* inten = echo + (size_t)N * C;

    const int nb_nrm = (N + D) / 4;
    hipLaunchKernelGGL(prep_kernel, dim3(nb_nrm + D / 128), dim3(256), 0, stream,
                       feat, exf, reps, Fn, Rt, N, N + D, D, C, nb_nrm);

    const int Dchunk = D / SPLITS;
    hipLaunchKernelGGL(fused_kernel, dim3(SPLITS, N / MT), dim3(256), 0, stream,
                       Fn, En, Rt, p, partial, N, D, C, Dchunk);

    hipLaunchKernelGGL(reduce_kernel, dim3(N * 32 / 256), dim3(256), 0, stream,
                       partial, echo, inten, N, SPLITS, C);
}